// Round 9
// baseline (67.817 us; speedup 1.0000x reference)
//
#include <hip/hip_runtime.h>

#define OUT_H 256
#define OUT_W 192
#define NPIX  (OUT_H * OUT_W)   // 49152
#define NPP   (NPIX / 2)        // 24576 pixel-pairs
#define NB    256
#define NC    25                 // N_CTRL
#define NL    28                 // NC + 3
#define BCHUNK 32

typedef float f4_t __attribute__((ext_vector_type(4)));

// ---------------------------------------------------------------------------
// Compile-time Li = inv(L) (first NC columns), fp64 Gauss-Jordan w/ partial
// pivoting, evaluated by the compiler. cx_log: ln via atanh series (~1e-16).
// ---------------------------------------------------------------------------
constexpr double cx_log(double x) {
    int k = 0;
    while (x > 1.5) { x *= 0.5; ++k; }
    while (x < 0.75) { x *= 2.0; --k; }
    double z = (x - 1.0) / (x + 1.0);
    double z2 = z * z;
    double t = z, s = 0.0;
    for (int i = 0; i < 16; ++i) { s += t / (double)(2 * i + 1); t *= z2; }
    return 2.0 * s + (double)k * 0.69314718055994530941723212145817656808;
}

struct LiMat { float v[NL][NC]; };

constexpr LiMat make_li() {
    double aug[NL][2 * NL] = {};
    const double ax[5] = {-1.0, -0.5, 0.0, 0.5, 1.0};
    for (int i = 0; i < NL; ++i)
        for (int j = 0; j < NL; ++j) {
            double v = 0.0;
            if (i < NC && j < NC) {
                double dx = ax[i / 5] - ax[j / 5];
                double dy = ax[i % 5] - ax[j % 5];
                double d2 = dx * dx + dy * dy;
                v = (d2 == 0.0) ? 0.0 : d2 * cx_log(d2);
            } else if (i < NC) {
                v = (j == NC) ? 1.0 : ((j == NC + 1) ? ax[i / 5] : ax[i % 5]);
            } else if (j < NC) {
                v = (i == NC) ? 1.0 : ((i == NC + 1) ? ax[j / 5] : ax[j % 5]);
            }
            aug[i][j] = (double)(float)v;   // mimic numpy's fp32 L build
        }
    for (int i = 0; i < NL; ++i) aug[i][NL + i] = 1.0;

    for (int k = 0; k < NL; ++k) {
        int p = k;
        double best = aug[k][k] < 0 ? -aug[k][k] : aug[k][k];
        for (int r = k + 1; r < NL; ++r) {
            double a = aug[r][k] < 0 ? -aug[r][k] : aug[r][k];
            if (a > best) { best = a; p = r; }
        }
        if (p != k)
            for (int j = k; j < 2 * NL; ++j) {
                double t = aug[k][j]; aug[k][j] = aug[p][j]; aug[p][j] = t;
            }
        const double ipv = 1.0 / aug[k][k];
        for (int j = k; j < 2 * NL; ++j) aug[k][j] *= ipv;
        for (int r = 0; r < NL; ++r) {
            if (r == k) continue;
            const double f = aug[r][k];
            if (f == 0.0) continue;
            for (int j = k; j < 2 * NL; ++j) aug[r][j] -= f * aug[k][j];
        }
    }
    LiMat o = {};
    for (int i = 0; i < NL; ++i)
        for (int j = 0; j < NC; ++j)
            o.v[i][j] = (float)aug[i][NL + j];
    return o;
}

constexpr LiMat LI_HOST = make_li();
__constant__ LiMat LI = LI_HOST;          // 2.8 KB, baked at compile time

// ---------------------------------------------------------------------------
// R6 structure exactly; template<NT> toggles ONLY the store instruction.
// Launched twice (idempotent): NT=true then NT=false. dur_us - 35.7 gives
// the cached variant's absolute main-kernel time (within-probe A/B).
// ---------------------------------------------------------------------------
template <bool NT>
__global__ __launch_bounds__(256) void tps_fused(const float* __restrict__ theta,
                                                 f4_t* __restrict__ out4) {
    __shared__ float sth[BCHUNK * 2 * NC];   // 1600 floats
    __shared__ float swc[BCHUNK][56];        // 32 x 56 coeffs (224B rows)

    const int tid = threadIdx.x;
    const int b0  = blockIdx.y * BCHUNK;

    // ---- stage theta slice (coalesced) ----
    #pragma unroll
    for (int k = 0; k < BCHUNK * 2 * NC; k += 256) {
        const int idx = k + tid;
        if (idx < BCHUNK * 2 * NC) sth[idx] = theta[b0 * 2 * NC + idx];
    }
    __syncthreads();

    const float axf[5] = {-1.f, -0.5f, 0.f, 0.5f, 1.f};

    // ---- coefficient block: b = tid>>3, group g = tid&7 handles rows 4g..4g+3
    {
        const int b = tid >> 3;
        const int g = tid & 7;
        if (g < 7) {
            float qx[NC], qy[NC];
            #pragma unroll
            for (int m = 0; m < NC; ++m) {
                qx[m] = sth[b * 2 * NC + m]      + axf[m / 5];
                qy[m] = sth[b * 2 * NC + NC + m] + axf[m % 5];
            }
            #pragma unroll
            for (int r = 0; r < 4; ++r) {
                const int n = g * 4 + r;
                float sx = 0.f, sy = 0.f;
                #pragma unroll
                for (int m = 0; m < NC; ++m) {
                    const float l = LI.v[n][m];
                    sx = fmaf(l, qx[m], sx);
                    sy = fmaf(l, qy[m], sy);
                }
                if (n < NC) { swc[b][n] = sx;              swc[b][NC + n] = sy; }
                else        { swc[b][50 + (n - NC)] = sx;  swc[b][53 + (n - NC)] = sy; }
            }
        }
    }

    // ---- per-thread radial basis for 2 adjacent pixels ----
    const int pp = blockIdx.x * 256 + tid;           // pixel-pair 0..24575
    const int h  = pp / (OUT_W / 2);
    const int w0 = (pp - h * (OUT_W / 2)) * 2;

    const float gy  = (h == OUT_H - 1) ? 1.f : (float)(-1.0 + h * (2.0 / (OUT_H - 1)));
    const float gx0 = (float)(-1.0 + w0 * (2.0 / (OUT_W - 1)));
    const float gx1 = (w0 + 1 == OUT_W - 1) ? 1.f
                                            : (float)(-1.0 + (w0 + 1) * (2.0 / (OUT_W - 1)));

    float U0[NC], U1[NC];
    #pragma unroll
    for (int n = 0; n < NC; ++n) {
        const float cx = axf[n / 5], cy = axf[n % 5];
        const float dy  = gy - cy;
        const float dx0 = gx0 - cx;
        const float d20 = dx0 * dx0 + dy * dy;
        U0[n] = (d20 == 0.f) ? 0.f : d20 * __logf(d20);
        const float dx1 = gx1 - cx;
        const float d21 = dx1 * dx1 + dy * dy;
        U1[n] = (d21 == 0.f) ? 0.f : d21 * __logf(d21);
    }

    __syncthreads();

    // ---- main loop over the block's 32 batches ----
    for (int bi = 0; bi < BCHUNK; ++bi) {
        float c[56];
        #pragma unroll
        for (int k = 0; k < 14; ++k)
            *(f4_t*)&c[k * 4] = *(const f4_t*)&swc[bi][k * 4];   // broadcast b128

        float X0 = fmaf(c[52], gy, fmaf(c[51], gx0, c[50]));
        float X1 = fmaf(c[52], gy, fmaf(c[51], gx1, c[50]));
        float Y0 = fmaf(c[55], gy, fmaf(c[54], gx0, c[53]));
        float Y1 = fmaf(c[55], gy, fmaf(c[54], gx1, c[53]));
        #pragma unroll
        for (int n = 0; n < NC; ++n) {
            X0 = fmaf(U0[n], c[n],      X0);
            X1 = fmaf(U1[n], c[n],      X1);
            Y0 = fmaf(U0[n], c[NC + n], Y0);
            Y1 = fmaf(U1[n], c[NC + n], Y1);
        }
        f4_t v; v.x = X0; v.y = Y0; v.z = X1; v.w = Y1;
        f4_t* dst = &out4[(size_t)(b0 + bi) * NPP + pp];
        if constexpr (NT) __builtin_nontemporal_store(v, dst);
        else              *dst = v;
    }
}

// ---------------------------------------------------------------------------
extern "C" void kernel_launch(void* const* d_in, const int* in_sizes, int n_in,
                              void* d_out, int out_size, void* d_ws, size_t ws_size,
                              hipStream_t stream) {
    const float* theta = (const float*)d_in[0];
    dim3 grid(NPP / 256, NB / BCHUNK);             // (96, 8) = 768 blocks
    // A/B measurement: NT variant (== R6), then cached variant overwriting
    // with identical values. dur_us - 35.7us isolates the cached time.
    tps_fused<true ><<<grid, 256, 0, stream>>>(theta, (f4_t*)d_out);
    tps_fused<false><<<grid, 256, 0, stream>>>(theta, (f4_t*)d_out);
}

// Round 10
// 34.215 us; speedup vs baseline: 1.9821x; 1.9821x over previous
//
#include <hip/hip_runtime.h>

#define OUT_H 256
#define OUT_W 192
#define NPIX  (OUT_H * OUT_W)   // 49152
#define NPP   (NPIX / 2)        // 24576 pixel-pairs
#define NB    256
#define NC    25                 // N_CTRL
#define NL    28                 // NC + 3
#define BCHUNK 16                // batches per block
#define PAIRS  2                 // pixel-pairs per thread (4 pixels)

typedef float f4_t __attribute__((ext_vector_type(4)));

// ---------------------------------------------------------------------------
// Compile-time Li = inv(L) (first NC columns), fp64 Gauss-Jordan w/ partial
// pivoting, evaluated by the compiler. cx_log: ln via atanh series (~1e-16).
// ---------------------------------------------------------------------------
constexpr double cx_log(double x) {
    int k = 0;
    while (x > 1.5) { x *= 0.5; ++k; }
    while (x < 0.75) { x *= 2.0; --k; }
    double z = (x - 1.0) / (x + 1.0);
    double z2 = z * z;
    double t = z, s = 0.0;
    for (int i = 0; i < 16; ++i) { s += t / (double)(2 * i + 1); t *= z2; }
    return 2.0 * s + (double)k * 0.69314718055994530941723212145817656808;
}

struct LiMat { float v[NL][NC]; };

constexpr LiMat make_li() {
    double aug[NL][2 * NL] = {};
    const double ax[5] = {-1.0, -0.5, 0.0, 0.5, 1.0};
    for (int i = 0; i < NL; ++i)
        for (int j = 0; j < NL; ++j) {
            double v = 0.0;
            if (i < NC && j < NC) {
                double dx = ax[i / 5] - ax[j / 5];
                double dy = ax[i % 5] - ax[j % 5];
                double d2 = dx * dx + dy * dy;
                v = (d2 == 0.0) ? 0.0 : d2 * cx_log(d2);
            } else if (i < NC) {
                v = (j == NC) ? 1.0 : ((j == NC + 1) ? ax[i / 5] : ax[i % 5]);
            } else if (j < NC) {
                v = (i == NC) ? 1.0 : ((i == NC + 1) ? ax[j / 5] : ax[j % 5]);
            }
            aug[i][j] = (double)(float)v;   // mimic numpy's fp32 L build
        }
    for (int i = 0; i < NL; ++i) aug[i][NL + i] = 1.0;

    for (int k = 0; k < NL; ++k) {
        int p = k;
        double best = aug[k][k] < 0 ? -aug[k][k] : aug[k][k];
        for (int r = k + 1; r < NL; ++r) {
            double a = aug[r][k] < 0 ? -aug[r][k] : aug[r][k];
            if (a > best) { best = a; p = r; }
        }
        if (p != k)
            for (int j = k; j < 2 * NL; ++j) {
                double t = aug[k][j]; aug[k][j] = aug[p][j]; aug[p][j] = t;
            }
        const double ipv = 1.0 / aug[k][k];
        for (int j = k; j < 2 * NL; ++j) aug[k][j] *= ipv;
        for (int r = 0; r < NL; ++r) {
            if (r == k) continue;
            const double f = aug[r][k];
            if (f == 0.0) continue;
            for (int j = k; j < 2 * NL; ++j) aug[r][j] -= f * aug[k][j];
        }
    }
    LiMat o = {};
    for (int i = 0; i < NL; ++i)
        for (int j = 0; j < NC; ++j)
            o.v[i][j] = (float)aug[i][NL + j];
    return o;
}

constexpr LiMat LI_HOST = make_li();
__constant__ LiMat LI = LI_HOST;          // 2.8 KB, baked at compile time

// ---------------------------------------------------------------------------
// Fused kernel, 2 pixel-pairs (4 px) per thread: halves chip-wide uniform
// ds_read issue work (the R9-diagnosed wall: ~27us of per-CU LDS-pipe busy
// at 2 px/thread). grid = (48, 16), 256 threads. Thread handles pairs
// pp0 = bx*512+tid and pp0+256 -> both stores stay unit-stride per wave.
//  swc row layout (stride 56): [0..24]=WX [25..49]=WY [50..52]=AX [53..55]=AY
// ---------------------------------------------------------------------------
__global__ __launch_bounds__(256) void tps_fused(const float* __restrict__ theta,
                                                 f4_t* __restrict__ out4) {
    __shared__ float sth[BCHUNK * 2 * NC];   // 800 floats
    __shared__ float swc[BCHUNK][56];        // 16 x 56 coeffs

    const int tid = threadIdx.x;
    const int b0  = blockIdx.y * BCHUNK;

    // ---- stage theta slice (coalesced) ----
    #pragma unroll
    for (int k = 0; k < BCHUNK * 2 * NC; k += 256) {
        const int idx = k + tid;
        if (idx < BCHUNK * 2 * NC) sth[idx] = theta[b0 * 2 * NC + idx];
    }
    __syncthreads();

    const float axf[5] = {-1.f, -0.5f, 0.f, 0.5f, 1.f};

    // ---- coefficient block: b = tid>>4 (16 thr/batch), g = tid&15 rows 2g,2g+1
    {
        const int b = tid >> 4;
        const int g = tid & 15;
        if (g < 14) {
            float qx[NC], qy[NC];
            #pragma unroll
            for (int m = 0; m < NC; ++m) {
                qx[m] = sth[b * 2 * NC + m]      + axf[m / 5];
                qy[m] = sth[b * 2 * NC + NC + m] + axf[m % 5];
            }
            #pragma unroll
            for (int r = 0; r < 2; ++r) {
                const int n = g * 2 + r;
                float sx = 0.f, sy = 0.f;
                #pragma unroll
                for (int m = 0; m < NC; ++m) {
                    const float l = LI.v[n][m];
                    sx = fmaf(l, qx[m], sx);
                    sy = fmaf(l, qy[m], sy);
                }
                if (n < NC) { swc[b][n] = sx;              swc[b][NC + n] = sy; }
                else        { swc[b][50 + (n - NC)] = sx;  swc[b][53 + (n - NC)] = sy; }
            }
        }
    }

    // ---- per-thread radial basis for 2 pixel-pairs (4 pixels) ----
    const int pp0 = blockIdx.x * (256 * PAIRS) + tid;   // first pair
    float gys[PAIRS], gx0s[PAIRS], gx1s[PAIRS];
    float U[2 * PAIRS][NC];
    #pragma unroll
    for (int q = 0; q < PAIRS; ++q) {
        const int pp = pp0 + q * 256;
        const int h  = pp / (OUT_W / 2);
        const int w0 = (pp - h * (OUT_W / 2)) * 2;
        const float gy  = (h == OUT_H - 1) ? 1.f : (float)(-1.0 + h * (2.0 / (OUT_H - 1)));
        const float gx0 = (float)(-1.0 + w0 * (2.0 / (OUT_W - 1)));
        const float gx1 = (w0 + 1 == OUT_W - 1) ? 1.f
                                                : (float)(-1.0 + (w0 + 1) * (2.0 / (OUT_W - 1)));
        gys[q] = gy; gx0s[q] = gx0; gx1s[q] = gx1;
        #pragma unroll
        for (int n = 0; n < NC; ++n) {
            const float cx = axf[n / 5], cy = axf[n % 5];
            const float dy  = gy - cy;
            const float dx0 = gx0 - cx;
            const float d20 = dx0 * dx0 + dy * dy;
            U[2 * q][n] = (d20 == 0.f) ? 0.f : d20 * __logf(d20);
            const float dx1 = gx1 - cx;
            const float d21 = dx1 * dx1 + dy * dy;
            U[2 * q + 1][n] = (d21 == 0.f) ? 0.f : d21 * __logf(d21);
        }
    }

    __syncthreads();

    // ---- main loop over the block's 16 batches ----
    for (int bi = 0; bi < BCHUNK; ++bi) {
        float c[56];
        #pragma unroll
        for (int k = 0; k < 14; ++k)
            *(f4_t*)&c[k * 4] = *(const f4_t*)&swc[bi][k * 4];   // broadcast b128

        const size_t sbase = (size_t)(b0 + bi) * NPP + pp0;
        #pragma unroll
        for (int q = 0; q < PAIRS; ++q) {
            const float gy = gys[q], gx0 = gx0s[q], gx1 = gx1s[q];
            float X0 = fmaf(c[52], gy, fmaf(c[51], gx0, c[50]));
            float X1 = fmaf(c[52], gy, fmaf(c[51], gx1, c[50]));
            float Y0 = fmaf(c[55], gy, fmaf(c[54], gx0, c[53]));
            float Y1 = fmaf(c[55], gy, fmaf(c[54], gx1, c[53]));
            #pragma unroll
            for (int n = 0; n < NC; ++n) {
                X0 = fmaf(U[2 * q][n],     c[n],      X0);
                X1 = fmaf(U[2 * q + 1][n], c[n],      X1);
                Y0 = fmaf(U[2 * q][n],     c[NC + n], Y0);
                Y1 = fmaf(U[2 * q + 1][n], c[NC + n], Y1);
            }
            f4_t v; v.x = X0; v.y = Y0; v.z = X1; v.w = Y1;
            __builtin_nontemporal_store(v, &out4[sbase + q * 256]);
        }
    }
}

// ---------------------------------------------------------------------------
extern "C" void kernel_launch(void* const* d_in, const int* in_sizes, int n_in,
                              void* d_out, int out_size, void* d_ws, size_t ws_size,
                              hipStream_t stream) {
    const float* theta = (const float*)d_in[0];
    dim3 grid(NPP / (256 * PAIRS), NB / BCHUNK);   // (48, 16) = 768 blocks
    tps_fused<<<grid, 256, 0, stream>>>(theta, (f4_t*)d_out);
}